// Round 19
// baseline (900.478 us; speedup 1.0000x reference)
//
#include <hip/hip_runtime.h>
#include <cstdint>
#include <cmath>

#define DEV __device__ __forceinline__

using f16 = _Float16;
typedef f16  f16x4 __attribute__((ext_vector_type(4)));
typedef f16  f16x8 __attribute__((ext_vector_type(8)));
typedef float f32x4 __attribute__((ext_vector_type(4)));

// problem sizes
constexpr int Bq = 4, Sq = 4096, Hq = 16;
constexpr int Tq = Bq * Sq;                 // 16384 tokens

// ---------------- workspace layout (~127 MiB total) ----------------
constexpr size_t OFF_WQKV = 0;                                    // [2048][1024] f16
constexpr size_t OFF_WSC  = OFF_WQKV + 2048ull * 1024 * 2;
constexpr size_t OFF_WCAT = OFF_WSC  + 2048ull * 1024 * 2;
constexpr size_t OFF_W1   = OFF_WCAT + 1024ull * 1024 * 2;
constexpr size_t OFF_W2   = OFF_W1   + 4096ull * 1024 * 2;
constexpr size_t OFF_BQKV = OFF_W2   + 1024ull * 4096 * 2;        // 2048 f32
constexpr size_t OFF_ZB   = OFF_BQKV + 8192;                      // (spare)
constexpr size_t OFF_Q    = OFF_ZB   + 4096;                      // q f16 [bh][s][32] ; h arena
constexpr size_t OFF_K    = OFF_Q    + (size_t)Tq * 512 * 2;      // k f16 [bh][s][32]
constexpr size_t OFF_P1   = OFF_K    + (size_t)Tq * 512 * 2;      // xn -> lt -> xatt ; g arena
constexpr size_t OFF_VT   = OFF_P1   + (size_t)Tq * 1024 * 2;     // vT f16 [bh][dv][s]
constexpr size_t OFF_KVA  = OFF_VT   + (size_t)Tq * 1024 * 2;     // (unused gap)
constexpr size_t OFF_KS   = OFF_KVA  + 64ull * 128 * 112 * 4;
constexpr size_t OFF_VST  = OFF_KS   + 64ull * 128 * 32 * 2;
constexpr size_t WS_NEED  = OFF_VST  + 64ull * 64 * 128 * 2;

// ---------------- async global->LDS staging with XOR swizzle ----------------
DEV void gload_lds16(const void* g, void* l) {
  __builtin_amdgcn_global_load_lds(
      (const __attribute__((address_space(1))) void*)g,
      (__attribute__((address_space(3))) void*)l, 16, 0, 0);
}

// 256-thread variant (non-GEMM users)
DEV void stage_swz(const char* gbase, long gstride, char* lds, int nbytes,
                   int rowlog, int swzmask) {
  int tid = threadIdx.x;
  for (int b0 = 0; b0 < nbytes; b0 += 4096) {
    int P = b0 + tid * 16;                        // phys LDS offset this lane fills
    int L = P ^ (((P >> rowlog) & swzmask) << 4); // logical offset (involution)
    long row  = L >> rowlog;
    int  colb = L & ((1 << rowlog) - 1);
    gload_lds16(gbase + row * gstride + colb, lds + b0 + (tid & ~63) * 16);
  }
}

// 512-thread variant (MODE 5 B-staging)
DEV void stage_swz512(const char* gbase, long gstride, char* lds, int nbytes,
                      int rowlog, int swzmask) {
  int tid = threadIdx.x;
  for (int b0 = 0; b0 < nbytes; b0 += 8192) {
    int P = b0 + tid * 16;
    int L = P ^ (((P >> rowlog) & swzmask) << 4);
    long row  = L >> rowlog;
    int  colb = L & ((1 << rowlog) - 1);
    gload_lds16(gbase + row * gstride + colb, lds + b0 + (tid & ~63) * 16);
  }
}

DEV float wave16_sum(float v) {
#pragma unroll
  for (int d = 1; d < 16; d <<= 1) v += __shfl_xor(v, d, 64);
  return v;
}

// ---------------- ALL weight transposes + casts in ONE launch ----------------
__global__ __launch_bounds__(256) void wcast_all_k(const float* __restrict__ w_q,
                                                   const float* __restrict__ w_kv,
                                                   const float* __restrict__ w_s,
                                                   const float* __restrict__ w_cat,
                                                   const float* __restrict__ w1,
                                                   const float* __restrict__ w2,
                                                   char* __restrict__ ws) {
  int id = blockIdx.x;
  const float* W; f16* Wt; int K, N, lid;
  if (id < 512)        { W = w_q;   Wt = (f16*)(ws + OFF_WQKV);              K = 1024; N = 512;  lid = id; }
  else if (id < 2048)  { W = w_kv;  Wt = (f16*)(ws + OFF_WQKV) + 512 * 1024; K = 1024; N = 1536; lid = id - 512; }
  else if (id < 4096)  { W = w_s;   Wt = (f16*)(ws + OFF_WSC);               K = 1024; N = 2048; lid = id - 2048; }
  else if (id < 5120)  { W = w_cat; Wt = (f16*)(ws + OFF_WCAT);              K = 1024; N = 1024; lid = id - 4096; }
  else if (id < 9216)  { W = w1;    Wt = (f16*)(ws + OFF_W1);                K = 1024; N = 4096; lid = id - 5120; }
  else                 { W = w2;    Wt = (f16*)(ws + OFF_W2);                K = 4096; N = 1024; lid = id - 9216; }
  int ntx = N >> 5;
  int n0 = (lid % ntx) * 32, k0 = (lid / ntx) * 32;
  __shared__ float tile[32][33];
  int tid = threadIdx.x, r = tid >> 5, c = tid & 31;
#pragma unroll
  for (int i = 0; i < 4; ++i)
    tile[r + i * 8][c] = W[(size_t)(k0 + r + i * 8) * N + n0 + c];
  __syncthreads();
#pragma unroll
  for (int i = 0; i < 4; ++i) {
    int rr = r + i * 8;
    Wt[(size_t)(n0 + rr) * K + k0 + c] = (f16)tile[c][rr];
  }
}

__global__ void bias_concat_k(const float* __restrict__ bq, const float* __restrict__ bkv,
                              float* __restrict__ out) {
  int i = blockIdx.x * 256 + threadIdx.x;   // 2048
  out[i] = (i < 512) ? bq[i] : bkv[i - 512];
}

// ---------------- RMSNorm ----------------
__global__ __launch_bounds__(256) void rmsnorm_k(const float* __restrict__ x,
                                                 const float* __restrict__ w,
                                                 f16* __restrict__ xn) {
  int row = blockIdx.x, tid = threadIdx.x;
  float4 v = ((const float4*)(x + (size_t)row * 1024))[tid];
  float ss = v.x * v.x + v.y * v.y + v.z * v.z + v.w * v.w;
#pragma unroll
  for (int d = 1; d < 64; d <<= 1) ss += __shfl_xor(ss, d, 64);
  __shared__ float red[4];
  if ((tid & 63) == 0) red[tid >> 6] = ss;
  __syncthreads();
  float tot = red[0] + red[1] + red[2] + red[3];
  float r = rsqrtf(tot * (1.0f / 1024.0f) + 1e-6f);
  float4 wv = ((const float4*)w)[tid];
  f16x4 o;
  o[0] = (f16)(v.x * r * wv.x); o[1] = (f16)(v.y * r * wv.y);
  o[2] = (f16)(v.z * r * wv.z); o[3] = (f16)(v.w * r * wv.w);
  *(f16x4*)(xn + (size_t)row * 1024 + tid * 4) = o;
}

// XCD region mapping (bijective). NSPLIT=2 -> square-ish regions for big-B GEMMs.
template <int NSPLIT>
DEV void xcd_map(int nwgx, int nbc, int bidl, int tileM, int tileN, long& m0, long& n0) {
  int cpx = (nwgx * nbc) >> 3;
  int xcd = bidl & 7, pos = bidl >> 3;
  int rn = nbc / NSPLIT;
  int rm = cpx / rn;
  int xm = xcd / NSPLIT, xn = xcd % NSPLIT;
  int nbi = xn * rn + pos / rm;
  int mb  = xm * rm + pos % rm;
  m0 = (long)mb * tileM;
  n0 = (long)nbi * tileN;
}

// ---------------- GEMM 128x128, 4 waves, dbuf + hoisted staging addresses: MODE 2 & 7 ----
template <int MODE, int NSPLIT = 1>
__global__ __launch_bounds__(256) void gemm_k(const f16* __restrict__ A, const f16* __restrict__ Bt,
                                              const float* __restrict__ bias,
                                              float* __restrict__ outF,
                                              const float* __restrict__ resid,
                                              const float* __restrict__ rsp,
                                              int M, int N, int K, int lda, int ldb) {
  __shared__ alignas(16) char smA[2][16384];
  __shared__ alignas(16) char smB[2][16384];
  int bidl = blockIdx.y * gridDim.x + blockIdx.x;
  long m0, n0;
  xcd_map<NSPLIT>(gridDim.x, gridDim.y, bidl, 128, 128, m0, n0);
  int tid = threadIdx.x, lane = tid & 63, wv = tid >> 6, wr = wv >> 1, wc = wv & 1;
  f32x4 acc[4][4] = {};

  const char* gA[4]; const char* gB[4]; int lo[4];
  long stepA = (MODE == 7) ? 524288 : 128;
  {
    const char* Abase;
    if (MODE == 7) Abase = (const char*)(A + (((m0 >> 12) * 16) * 4096 + (m0 & 4095)) * 64);
    else           Abase = (const char*)(A + m0 * lda);
    const char* Bbase = (const char*)(Bt + n0 * ldb);
    long astr = (MODE == 7) ? 128 : (long)lda * 2;
#pragma unroll
    for (int c = 0; c < 4; ++c) {
      int P = c * 4096 + tid * 16;
      int L = P ^ (((P >> 7) & 7) << 4);
      long row = L >> 7; int colb = L & 127;
      lo[c] = c * 4096 + (tid & ~63) * 16;
      gA[c] = Abase + row * astr + colb;
      gB[c] = Bbase + row * ((long)ldb * 2) + colb;
    }
  }
  auto stageAB = [&](int buf, int t) {
#pragma unroll
    for (int c = 0; c < 4; ++c) gload_lds16(gB[c] + (long)t * 128, smB[buf] + lo[c]);
#pragma unroll
    for (int c = 0; c < 4; ++c) gload_lds16(gA[c] + (long)t * stepA, smA[buf] + lo[c]);
  };

  int T = K >> 6;
  stageAB(0, 0);
  __syncthreads();
  int cur = 0;
  for (int t = 0; t < T; ++t) {
    if (t + 1 < T) stageAB(cur ^ 1, t + 1);
#pragma unroll
    for (int kk = 0; kk < 2; ++kk) {
      int kbyte = kk * 64 + (lane >> 4) * 16;
      f16x8 aF[4], bF[4];
#pragma unroll
      for (int m = 0; m < 4; ++m) {
        int L = (wr * 64 + m * 16 + (lane & 15)) * 128 + kbyte;
        aF[m] = *(const f16x8*)(smA[cur] + (L ^ (((L >> 7) & 7) << 4)));
      }
#pragma unroll
      for (int n = 0; n < 4; ++n) {
        int L = (wc * 64 + n * 16 + (lane & 15)) * 128 + kbyte;
        bF[n] = *(const f16x8*)(smB[cur] + (L ^ (((L >> 7) & 7) << 4)));
      }
#pragma unroll
      for (int m = 0; m < 4; ++m)
#pragma unroll
        for (int n = 0; n < 4; ++n)
          acc[m][n] = __builtin_amdgcn_mfma_f32_16x16x32_f16(aF[m], bF[n], acc[m][n], 0, 0, 0);
    }
    __syncthreads();
    cur ^= 1;
  }
  float rsv = rsp[0];
#pragma unroll
  for (int m = 0; m < 4; ++m)
#pragma unroll
    for (int n = 0; n < 4; ++n) {
      long gn = n0 + wc * 64 + n * 16 + (lane & 15);
      float bv = bias[gn];
      long rbase = m0 + wr * 64 + m * 16 + (lane >> 4) * 4;
#pragma unroll
      for (int i = 0; i < 4; ++i) {
        long gm = rbase + i;
        float v = acc[m][n][i] + bv;
        long idx = gm * N + gn;
        outF[idx] = resid[idx] + v * rsv;
      }
    }
}

// ---------------- GEMM 256x256, 8 waves (2x4): MODE 3,4 single-buffer (64KB -> 2 blocks/CU);
// ---------------- MODE 5 legacy dbuf.  Cross-block TLP is the latency hiding (m114). ----
template <int MODE, int NSPLIT = 1>
__global__ __launch_bounds__(512, 2) void gemm256_k(const f16* __restrict__ A, const f16* __restrict__ Bt,
                                                    const float* __restrict__ bias,
                                                    f16* __restrict__ o1, f16* __restrict__ o2,
                                                    f16* __restrict__ o3,
                                                    const float* __restrict__ resid,
                                                    int M, int N, int K, int lda, int ldb, int pp) {
  constexpr int NBUF = (MODE == 5) ? 2 : 1;
  __shared__ alignas(16) char smA[NBUF][32768];
  __shared__ alignas(16) char smB[NBUF][32768];
  int bidl = blockIdx.y * gridDim.x + blockIdx.x;
  long m0, n0;
  xcd_map<NSPLIT>(gridDim.x, gridDim.y, bidl, 256, 256, m0, n0);
  int tid = threadIdx.x, lane = tid & 63, wv = tid >> 6;   // wv 0..7
  int wr = wv >> 2, wc = wv & 3;                            // 2 x 4 wave grid
  long t0 = 0;
  int bq = 0;
  if (MODE == 5) {
    long mbl = m0 >> 8;                        // original flat m block index
    bq = (int)(mbl >> 3); int sb = (int)(mbl & 7);
    m0 = (long)sb * 256;                       // local s base within the half
    t0 = (long)bq * 4096 + (long)pp * 2048 + m0;
  }
  f32x4 acc[8][4] = {};
  const char* Bb = (const char*)(Bt + n0 * ldb);

  if constexpr (MODE == 5) {
    auto stageAB5 = [&](int buf, int k0) {
      stage_swz512(Bb + (long)k0 * 2, (long)ldb * 2, smB[buf], 32768, 7, 7);
      int P = tid * 16;
#pragma unroll
      for (int b0 = 0; b0 < 32768; b0 += 8192) {
        int PP = b0 + P;
        int L = PP ^ (((PP >> 7) & 7) << 4);
        int row = L >> 7, colf = (L & 127) >> 1;
        const float* src = resid + (size_t)(t0 + row) * 1024 + k0 + colf;
        float4 u0 = *(const float4*)src;
        float4 u1 = *(const float4*)(src + 4);
        f16x8 o;
        o[0] = (f16)u0.x; o[1] = (f16)u0.y; o[2] = (f16)u0.z; o[3] = (f16)u0.w;
        o[4] = (f16)u1.x; o[5] = (f16)u1.y; o[6] = (f16)u1.z; o[7] = (f16)u1.w;
        *(f16x8*)(smA[buf] + PP) = o;
      }
    };
    stageAB5(0, 0);
    __syncthreads();
    int cur = 0;
    for (int k0 = 0; k0 < K; k0 += 64) {
      if (k0 + 64 < K) stageAB5(cur ^ 1, k0 + 64);
#pragma unroll
      for (int kk = 0; kk < 2; ++kk) {
        int kb2 = kk * 64 + (lane >> 4) * 16;
        f16x8 aF[8], bF[4];
#pragma unroll
        for (int m = 0; m < 8; ++m) {
          int L = (wr * 128 + m * 16 + (lane & 15)) * 128 + kb2;
          aF[m] = *(const f16x8*)(smA[cur] + (L ^ (((L >> 7) & 7) << 4)));
        }
#pragma unroll
        for (int n = 0; n < 4; ++n) {
          int L = (wc * 64 + n * 16 + (lane & 15)) * 128 + kb2;
          bF[n] = *(const f16x8*)(smB[cur] + (L ^ (((L >> 7) & 7) << 4)));
        }
#pragma unroll
        for (int m = 0; m < 8; ++m)
#pragma unroll
          for (int n = 0; n < 4; ++n)
            acc[m][n] = __builtin_amdgcn_mfma_f32_16x16x32_f16(aF[m], bF[n], acc[m][n], 0, 0, 0);
      }
      __syncthreads();
      cur ^= 1;
    }
  } else {
    const char* gA[4]; const char* gB[4]; int lo[4];
    {
      const char* Abase = (const char*)(A + m0 * lda);
#pragma unroll
      for (int c = 0; c < 4; ++c) {
        int P = c * 8192 + tid * 16;
        int L = P ^ (((P >> 7) & 7) << 4);
        long row = L >> 7; int colb = L & 127;
        lo[c] = c * 8192 + (tid & ~63) * 16;
        gA[c] = Abase + row * ((long)lda * 2) + colb;
        gB[c] = Bb + row * ((long)ldb * 2) + colb;
      }
    }
    auto stageAB = [&](int t) {
#pragma unroll
      for (int c = 0; c < 4; ++c) gload_lds16(gB[c] + (long)t * 128, smB[0] + lo[c]);
#pragma unroll
      for (int c = 0; c < 4; ++c) gload_lds16(gA[c] + (long)t * 128, smA[0] + lo[c]);
    };
    int T = K >> 6;
    for (int t = 0; t < T; ++t) {
      if (t > 0) __syncthreads();      // prior compute's LDS readers done
      stageAB(t);
      __syncthreads();                 // staged + visible (vmcnt drained by sync)
#pragma unroll
      for (int kk = 0; kk < 2; ++kk) {
        int kb2 = kk * 64 + (lane >> 4) * 16;
        f16x8 aF[8], bF[4];
#pragma unroll
        for (int m = 0; m < 8; ++m) {
          int L = (wr * 128 + m * 16 + (lane & 15)) * 128 + kb2;
          aF[m] = *(const f16x8*)(smA[0] + (L ^ (((L >> 7) & 7) << 4)));
        }
#pragma unroll
        for (int n = 0; n < 4; ++n) {
          int L = (wc * 64 + n * 16 + (lane & 15)) * 128 + kb2;
          bF[n] = *(const f16x8*)(smB[0] + (L ^ (((L >> 7) & 7) << 4)));
        }
#pragma unroll
        for (int m = 0; m < 8; ++m)
#pragma unroll
          for (int n = 0; n < 4; ++n)
            acc[m][n] = __builtin_amdgcn_mfma_f32_16x16x32_f16(aF[m], bF[n], acc[m][n], 0, 0, 0);
      }
    }
  }
#pragma unroll
  for (int m = 0; m < 8; ++m)
#pragma unroll
    for (int n = 0; n < 4; ++n) {
      long gn = n0 + wc * 64 + n * 16 + (lane & 15);
      float bv = bias[gn];
      long rbase = m0 + wr * 128 + m * 16 + (lane >> 4) * 4;
      if (MODE == 4) {
        long b = rbase >> 12, s = rbase & 4095;
        if (gn < 512) {
          long h = gn >> 5, dk = gn & 31;
#pragma unroll
          for (int i = 0; i < 4; ++i)
            o1[(((size_t)b * 16 + h) * 4096 + s + i) * 32 + dk] = (f16)(acc[m][n][i] + bv);
        } else {
          long c2 = gn - 512, h = c2 / 96, j = c2 % 96;
          if (j < 32) {
#pragma unroll
            for (int i = 0; i < 4; ++i)
              o2[(((size_t)b * 16 + h) * 4096 + s + i) * 32 + j] = (f16)(acc[m][n][i] + bv);
          } else {
            f16x4 pk;
#pragma unroll
            for (int i = 0; i < 4; ++i) pk[i] = (f16)(acc[m][n][i] + bv);
            *(f16x4*)(o3 + (((size_t)b * 16 + h) * 64 + (j - 32)) * 4096 + s) = pk;
          }
        }
      } else {
#pragma unroll
        for (int i = 0; i < 4; ++i) {
          long gm = rbase + i;
          float v = acc[m][n][i] + bv;
          if (MODE == 3) {
            float u = v * 0.7978845608028654f * (1.f + 0.044715f * v * v);
            float e = __expf(fminf(2.f * u, 80.f));
            o1[gm * N + gn] = (f16)(v * (e / (e + 1.f)));
          } else {  // MODE 5: lt[(bq*2048+gn)*2048 + s_local]
            o1[((size_t)bq * 2048 + gn) * 2048 + gm] = (f16)v;
          }
        }
      }
    }
}

// ---------------- kv_s partials: fixed-offset softmax, (nsb, s-chunk) parallel ----------------
__global__ __launch_bounds__(256) void kvs_k(const f16* __restrict__ lt,
                                             const f16* __restrict__ kh,
                                             const f16* __restrict__ vT,
                                             const float* __restrict__ mask,
                                             float* __restrict__ pacc, int pass) {
  int gx = blockIdx.x, nsb = gx & 3, sc = gx >> 2;
  int h = blockIdx.y, b = blockIdx.z;
  int bh = b * 16 + h;
  __shared__ alignas(16) char smA[4096];        // p [32 ns][64 s] swizzled
  __shared__ alignas(16) f16 smB[112][88];      // [col j][s]; rows 96..111 den/zero
  int tid = threadIdx.x, lane = tid & 63, w = tid >> 6;
  int mf = w >> 1, nb0 = (w & 1) * 4, nfr = (w & 1) ? 3 : 4;
  for (int idx = tid; idx < 16 * 64; idx += 256) {
    int r = 96 + (idx >> 6), c2 = idx & 63;
    smB[r][c2] = (r == 96) ? (f16)1.0f : (f16)0.0f;
  }
  f32x4 acc[4] = {};
  const f16* ltb = lt + ((size_t)bh * 128 + nsb * 32) * 2048;
  for (int it = 0; it < 4; ++it) {
    int sl0 = sc * 256 + it * 64;              // within-half s base
    int s0g = pass * 2048 + sl0;               // global s base
    __syncthreads();
    {   // A: p = mask>0 ? exp(l-8) : 0
      int P = tid * 16;
      int L = P ^ (((P >> 7) & 7) << 4);
      int row = L >> 7, colf = (L & 127) >> 1;
      f16x8 lv = *(const f16x8*)(ltb + (size_t)row * 2048 + sl0 + colf);
      const float* mrow = mask + (size_t)b * 4096 + s0g + colf;
      float4 m0v = *(const float4*)mrow, m1v = *(const float4*)(mrow + 4);
      float mm[8] = {m0v.x, m0v.y, m0v.z, m0v.w, m1v.x, m1v.y, m1v.z, m1v.w};
      f16x8 o;
#pragma unroll
      for (int j = 0; j < 8; ++j)
        o[j] = (f16)((mm[j] > 0.f) ? expf((float)lv[j] - 8.0f) : 0.0f);
      *(f16x8*)(smA + P) = o;
    }
    {   // B: k part -> rows 0..31
      int sl = tid >> 2, jg = (tid & 3) * 8;
      f16x8 u = *(const f16x8*)(kh + ((size_t)bh * 4096 + s0g + sl) * 32 + jg);
#pragma unroll
      for (int j = 0; j < 8; ++j) smB[jg + j][sl] = u[j];
    }
#pragma unroll
    for (int half = 0; half < 2; ++half) {   // B: v part (vT, vectorized) -> rows 32..95
      int task = tid + half * 256;
      int dv = task >> 3, sl0v = (task & 7) * 8;
      f16x8 u = *(const f16x8*)(vT + ((size_t)bh * 64 + dv) * 4096 + s0g + sl0v);
      *(f16x8*)(&smB[32 + dv][sl0v]) = u;
    }
    __syncthreads();
#pragma unroll
    for (int kk = 0; kk < 2; ++kk) {
      int kbyte = kk * 64 + (lane >> 4) * 16;
      int L = (mf * 16 + (lane & 15)) * 128 + kbyte;
      f16x8 aF = *(const f16x8*)(smA + (L ^ (((L >> 7) & 7) << 4)));
#pragma unroll
      for (int n = 0; n < 4; ++n)
        if (n < nfr) {
          f16x8 bF = *(const f16x8*)((const char*)smB + ((nb0 + n) * 16 + (lane & 15)) * 176 + kbyte);
          acc[n] = __builtin_amdgcn_mfma_f32_16x16x32_f16(aF, bF, acc[n], 0, 0, 0);
        }
    }
  }
  int slot = pass * 8 + sc;
  float* pb = pacc + (((size_t)bh * 4 + nsb) * 16 + slot) * 3584;
#pragma unroll
  for (int n = 0; n < 4; ++n)
    if (n < nfr) {
      int col = (nb0 + n) * 16 + (lane & 15);
#pragma unroll
      for (int i = 0; i < 4; ++i) {
        int nsrow = mf * 16 + (lane >> 4) * 4 + i;
        pb[(size_t)nsrow * 112 + col] = acc[n][i];
      }
    }
}

__global__ __launch_bounds__(256) void kvs_fin_k(const float* __restrict__ pacc,
                                                 f16* __restrict__ ks, f16* __restrict__ vst) {
  int bh = blockIdx.x, tid = threadIdx.x;
  __shared__ float den[128];
  const float* base = pacc + (size_t)bh * 4 * 16 * 3584;
  if (tid < 128) {
    int nsb = tid >> 5, nsl = tid & 31;
    float d = 0.f;
#pragma unroll
    for (int slot = 0; slot < 16; ++slot)
      d += base[((size_t)nsb * 16 + slot) * 3584 + (size_t)nsl * 112 + 96];
    den[tid] = d;
  }
  __syncthreads();
  for (int e = tid; e < 12288; e += 256) {
    int ns = e / 96, j = e % 96;
    int nsb = ns >> 5, nsl = ns & 31;
    float sv = 0.f;
#pragma unroll
    for (int slot = 0; slot < 16; ++slot)
      sv += base[((size_t)nsb * 16 + slot) * 3584 + (size_t)nsl * 112 + j];
    float v = sv / den[ns];
    if (j < 32) ks[((size_t)bh * 128 + ns) * 32 + j] = (f16)v;
    else        vst[((size_t)bh * 64 + (j - 32)) * 128 + ns] = (f16)v;
  }
}

// ---------------- merged attention, QBLK=64, single-buffer, no-max softmax ----------------
__global__ __launch_bounds__(256) void att_k(const f16* __restrict__ qh,
                                             const f16* __restrict__ kh,
                                             const f16* __restrict__ vTh,
                                             const f16* __restrict__ ksb,
                                             const f16* __restrict__ vstb,
                                             f16* __restrict__ xatt) {
  int ntj = blockIdx.x, h = blockIdx.y, b = blockIdx.z;
  int nt = ((ntj & 7) << 3) | (ntj >> 3);     // 64 q-tiles, 8 consecutive per XCD
  int bh = b * 16 + h, s0 = nt * 64;
  __shared__ alignas(16) char smQ[4096];      // Q [64 q][32 dk] swz6/3
  __shared__ alignas(16) char smK[4096];      // K chunk [64 k][32 dk] swz6/3
  __shared__ alignas(16) char smV[8192];      // V^T chunk [64 dv][64 k] swz7/7
  __shared__ alignas(16) f16 smP[4][16][72];  // per-wave P [16 q][64 k]
  int tid = threadIdx.x, lane = tid & 63, w = tid >> 6;
  const float scale = 0.17677669529663687f;
  stage_swz((const char*)(qh + ((size_t)bh * 4096 + s0) * 32), 64, smQ, 4096, 6, 3);

  float lrun[4], l1[4];
#pragma unroll
  for (int i = 0; i < 4; ++i) { lrun[i] = 0.f; l1[i] = 0.f; }
  f32x4 o2[4] = {}, o1[4] = {};

  // 5 uniform chunks: 0..2 window (key base s0-128/s0-64/s0), 3..4 summary
  for (int c = 0; c < 5; ++c) {
    bool win = (c < 3);
    long kb = (long)s0 + (c - 2) * 64;
    if (win && kb < 0) continue;              // block-uniform
    __syncthreads();                          // prior PV reads of smK/smV done
    if (win) {
      stage_swz((const char*)(kh + ((size_t)bh * 4096 + kb) * 32), 64, smK, 4096, 6, 3);
      stage_swz((const char*)(vTh + (size_t)bh * 64 * 4096 + kb), 8192, smV, 8192, 7, 7);
    } else {
      int sc = c - 3;
      stage_swz((const char*)(ksb + ((size_t)bh * 128 + sc * 64) * 32), 64, smK, 4096, 6, 3);
      stage_swz((const char*)(vstb + (size_t)bh * 64 * 128 + sc * 64), 256, smV, 8192, 7, 7);
    }
    __syncthreads();                          // K+V (and Q on first iter) staged
    // QK^T: 16 q-rows per wave x 64 keys
    f32x4 s[4] = {};
    {
      int kbyte = (lane >> 4) * 16;
      int Lq = (w * 16 + (lane & 15)) * 64 + kbyte;
      f16x8 aF = *(const f16x8*)(smQ + (Lq ^ (((Lq >> 6) & 3) << 4)));
#pragma unroll
      for (int n = 0; n < 4; ++n) {
        int Lk = (n * 16 + (lane & 15)) * 64 + kbyte;
        f16x8 bF = *(const f16x8*)(smK + (Lk ^ (((Lk >> 6) & 3) << 4)));
        s[n] = __builtin_amdgcn_mfma_f32_16x16x32_f16(aF, bF, s[n], 0, 0, 0);
      }
    }
    // no-max softmax accumulate (window and summary keep separate l/o)
    float* lr = win ? lrun : l1;
    f32x4* oo = win ? o2 : o1;
#pragma unroll
    for (int i = 0; i < 4; ++i) {
      int a2 = w * 16 + (lane >> 4) * 4 + i;
      float sum = 0.f;
#pragma unroll
      for (int n = 0; n < 4; ++n) {
        int kl = n * 16 + (lane & 15);
        bool valid = !win || (c == 1) || (c == 0 ? (kl >= a2) : (kl <= a2));
        float p = valid ? __expf(fminf(s[n][i] * scale, 10.f)) : 0.f;
        s[n][i] = p; sum += p;
      }
      lr[i] += wave16_sum(sum);
    }
    // P -> per-wave LDS slice (same-wave dependency; no block barrier needed)
#pragma unroll
    for (int n = 0; n < 4; ++n)
#pragma unroll
      for (int i = 0; i < 4; ++i)
        smP[w][(lane >> 4) * 4 + i][n * 16 + (lane & 15)] = (f16)s[n][i];
    // PV: K-dim 64 -> 2 mfma steps
#pragma unroll
    for (int kk = 0; kk < 2; ++kk) {
      int kb2 = kk * 64 + (lane >> 4) * 16;
      f16x8 aP = *(const f16x8*)((const char*)smP[w] + (lane & 15) * 144 + kb2);
#pragma unroll
      for (int n = 0; n < 4; ++n) {
        int dv = n * 16 + (lane & 15);
        int Lv = dv * 128 + kb2;
        f16x8 bV = *(const f16x8*)(smV + (Lv ^ (((Lv >> 7) & 7) << 4)));
        oo[n] = __builtin_amdgcn_mfma_f32_16x16x32_f16(aP, bV, oo[n], 0, 0, 0);
      }
    }
  }
  // epilogue: contiguous head-blocked write
  f16* xb = xatt + ((size_t)bh * 4096 + s0) * 64;
#pragma unroll
  for (int n = 0; n < 4; ++n)
#pragma unroll
    for (int i = 0; i < 4; ++i) {
      int row = w * 16 + (lane >> 4) * 4 + i, dv = n * 16 + (lane & 15);
      xb[(size_t)row * 64 + dv] = (f16)(o2[n][i] / lrun[i] + o1[n][i] / l1[i]);
    }
}

// ---------------- diagnostic sentinel ----------------
__global__ void sentinel_k(float* out, size_t n, float val) {
  size_t i = (size_t)blockIdx.x * 256 + threadIdx.x;
  size_t stride = (size_t)gridDim.x * 256;
  for (; i < n; i += stride) out[i] = val;
}

extern "C" void kernel_launch(void* const* d_in, const int* in_sizes, int n_in,
                              void* d_out, int out_size, void* d_ws, size_t ws_size,
                              hipStream_t stream) {
  float* xo = (float*)d_out;
  if (ws_size < WS_NEED) {   // diagnostic: encode ws_size into the output
    float val = -(1000.0f + (float)(ws_size / 1000000ull));
    sentinel_k<<<2048, 256, 0, stream>>>(xo, (size_t)out_size, val);
    return;
  }
  const float* x     = (const float*)d_in[0];
  const float* mask  = (const float*)d_in[1];
  const float* rsp   = (const float*)d_in[2];
  const float* w_q   = (const float*)d_in[3];
  const float* b_q   = (const float*)d_in[4];
  const float* w_kv  = (const float*)d_in[5];
  const float* b_kv  = (const float*)d_in[6];
  const float* w_s   = (const float*)d_in[7];
  const float* b_s   = (const float*)d_in[8];
  const float* w_cat = (const float*)d_in[9];
  const float* b_cat = (const float*)d_in[10];
  const float* n1w   = (const float*)d_in[11];
  const float* n2w   = (const float*)d_in[12];
  const float* w1    = (const float*)d_in[13];
  const float* b1    = (const float*)d_in[14];
  const float* w2    = (const float*)d_in[15];
  const float* b2    = (const float*)d_in[16];
  char* ws = (char*)d_ws;

  f16*   wqkv_t = (f16*)(ws + OFF_WQKV);
  f16*   ws_t   = (f16*)(ws + OFF_WSC);
  f16*   wcat_t = (f16*)(ws + OFF_WCAT);
  f16*   w1_t   = (f16*)(ws + OFF_W1);
  f16*   w2_t   = (f16*)(ws + OFF_W2);
  float* bqkv   = (float*)(ws + OFF_BQKV);
  f16*   q_h    = (f16*)(ws + OFF_Q);
  f16*   k_h    = (f16*)(ws + OFF_K);
  f16*   h_h    = (f16*)(ws + OFF_Q);     // alias: q+k dead at MLP time
  f16*   xn_h   = (f16*)(ws + OFF_P1);
  f16*   lt16   = (f16*)(ws + OFF_P1);    // alias: xn dead after qkv gemm
  f16*   xatt_h = (f16*)(ws + OFF_P1);    // alias: lt dead after kvs
  f16*   g_h    = (f16*)(ws + OFF_P1);    // alias: spans P1+VT at MLP time (67 MB)
  f16*   vT_h   = (f16*)(ws + OFF_VT);
  f16*   ks_h   = (f16*)(ws + OFF_KS);
  f16*   vst_h  = (f16*)(ws + OFF_VST);

  // weight prep: one launch for all transposes + bias concat
  wcast_all_k<<<13312, 256, 0, stream>>>(w_q, w_kv, w_s, w_cat, w1, w2, ws);
  bias_concat_k<<<8, 256, 0, stream>>>(b_q, b_kv, bqkv);

  // norm1 -> xn
  rmsnorm_k<<<Tq, 256, 0, stream>>>(x, n1w, xn_h);
  // qkv projection (256² single-buf, 2 blocks/CU) -> q/k f16, v transposed f16
  gemm256_k<4><<<dim3(64, 8), 512, 0, stream>>>(xn_h, wqkv_t, bqkv, q_h, k_h, vT_h,
                                                nullptr, Tq, 2048, 1024, 1024, 1024, 0);
  // summary path: two s-halves; kvs partials go to d_out scratch (dead until out-proj)
  for (int p = 0; p < 2; ++p) {
    gemm256_k<5><<<dim3(32, 8), 512, 0, stream>>>(nullptr, ws_t, b_s, lt16, nullptr, nullptr,
                                                  x, 8192, 2048, 1024, 0, 1024, p);
    kvs_k<<<dim3(32, 16, 4), 256, 0, stream>>>(lt16, k_h, vT_h, mask, xo, p);
  }
  kvs_fin_k<<<64, 256, 0, stream>>>(xo, ks_h, vst_h);
  // merged attention (QBLK=64, no-max softmax) -> xatt [b][h][s][64] (over lt)
  att_k<<<dim3(64, 16, 4), 256, 0, stream>>>(q_h, k_h, vT_h, ks_h, vst_h, xatt_h);
  // out projection + residual -> d_out (f32); A head-blocked (128² dbuf, 1024 blocks)
  gemm_k<7><<<dim3(128, 8), 256, 0, stream>>>(xatt_h, wcat_t, b_cat, xo,
                                              x, rsp, Tq, 1024, 1024, 0, 1024);
  // MLP: norm2 -> h (over q+k); two M-chunks of 8192 tokens, g = 67 MB arena
  rmsnorm_k<<<Tq, 256, 0, stream>>>(xo, n2w, h_h);
  for (int mc = 0; mc < 2; ++mc) {
    const f16* hA = h_h + (size_t)mc * 8192 * 1024;
    float* xoc = xo + (size_t)mc * 8192 * 1024;
    gemm256_k<3, 2><<<dim3(32, 16), 512, 0, stream>>>(hA, w1_t, b1, g_h, nullptr, nullptr,
                                                      nullptr, 8192, 4096, 1024, 1024, 1024, 0);
    gemm_k<2, 2><<<dim3(64, 8), 256, 0, stream>>>(g_h, w2_t, b2, xoc,
                                                  xoc, rsp, 8192, 1024, 4096, 4096, 4096);
  }
}

// Round 20
// 860.121 us; speedup vs baseline: 1.0469x; 1.0469x over previous
//
#include <hip/hip_runtime.h>
#include <cstdint>
#include <cmath>

#define DEV __device__ __forceinline__

using f16 = _Float16;
typedef f16  f16x4 __attribute__((ext_vector_type(4)));
typedef f16  f16x8 __attribute__((ext_vector_type(8)));
typedef float f32x4 __attribute__((ext_vector_type(4)));

// problem sizes
constexpr int Bq = 4, Sq = 4096, Hq = 16;
constexpr int Tq = Bq * Sq;                 // 16384 tokens

// ---------------- workspace layout (~127 MiB total) ----------------
constexpr size_t OFF_WQKV = 0;                                    // [2048][1024] f16
constexpr size_t OFF_WSC  = OFF_WQKV + 2048ull * 1024 * 2;
constexpr size_t OFF_WCAT = OFF_WSC  + 2048ull * 1024 * 2;
constexpr size_t OFF_W1   = OFF_WCAT + 1024ull * 1024 * 2;
constexpr size_t OFF_W2   = OFF_W1   + 4096ull * 1024 * 2;
constexpr size_t OFF_BQKV = OFF_W2   + 1024ull * 4096 * 2;        // 2048 f32
constexpr size_t OFF_ZB   = OFF_BQKV + 8192;                      // (spare)
constexpr size_t OFF_Q    = OFF_ZB   + 4096;                      // q f16 [bh][s][32] ; h arena
constexpr size_t OFF_K    = OFF_Q    + (size_t)Tq * 512 * 2;      // k f16 [bh][s][32]
constexpr size_t OFF_P1   = OFF_K    + (size_t)Tq * 512 * 2;      // xn -> lt -> xatt ; g arena
constexpr size_t OFF_VT   = OFF_P1   + (size_t)Tq * 1024 * 2;     // vT f16 [bh][dv][s]
constexpr size_t OFF_KVA  = OFF_VT   + (size_t)Tq * 1024 * 2;     // (unused gap)
constexpr size_t OFF_KS   = OFF_KVA  + 64ull * 128 * 112 * 4;
constexpr size_t OFF_VST  = OFF_KS   + 64ull * 128 * 32 * 2;
constexpr size_t WS_NEED  = OFF_VST  + 64ull * 64 * 128 * 2;

// ---------------- async global->LDS staging with XOR swizzle ----------------
DEV void gload_lds16(const void* g, void* l) {
  __builtin_amdgcn_global_load_lds(
      (const __attribute__((address_space(1))) void*)g,
      (__attribute__((address_space(3))) void*)l, 16, 0, 0);
}

// 256-thread variant (non-GEMM users)
DEV void stage_swz(const char* gbase, long gstride, char* lds, int nbytes,
                   int rowlog, int swzmask) {
  int tid = threadIdx.x;
  for (int b0 = 0; b0 < nbytes; b0 += 4096) {
    int P = b0 + tid * 16;                        // phys LDS offset this lane fills
    int L = P ^ (((P >> rowlog) & swzmask) << 4); // logical offset (involution)
    long row  = L >> rowlog;
    int  colb = L & ((1 << rowlog) - 1);
    gload_lds16(gbase + row * gstride + colb, lds + b0 + (tid & ~63) * 16);
  }
}

// 512-thread variant (MODE 5 B-staging)
DEV void stage_swz512(const char* gbase, long gstride, char* lds, int nbytes,
                      int rowlog, int swzmask) {
  int tid = threadIdx.x;
  for (int b0 = 0; b0 < nbytes; b0 += 8192) {
    int P = b0 + tid * 16;
    int L = P ^ (((P >> rowlog) & swzmask) << 4);
    long row  = L >> rowlog;
    int  colb = L & ((1 << rowlog) - 1);
    gload_lds16(gbase + row * gstride + colb, lds + b0 + (tid & ~63) * 16);
  }
}

DEV float wave16_sum(float v) {
#pragma unroll
  for (int d = 1; d < 16; d <<= 1) v += __shfl_xor(v, d, 64);
  return v;
}

// ---------------- ALL weight transposes + casts in ONE launch ----------------
__global__ __launch_bounds__(256) void wcast_all_k(const float* __restrict__ w_q,
                                                   const float* __restrict__ w_kv,
                                                   const float* __restrict__ w_s,
                                                   const float* __restrict__ w_cat,
                                                   const float* __restrict__ w1,
                                                   const float* __restrict__ w2,
                                                   char* __restrict__ ws) {
  int id = blockIdx.x;
  const float* W; f16* Wt; int K, N, lid;
  if (id < 512)        { W = w_q;   Wt = (f16*)(ws + OFF_WQKV);              K = 1024; N = 512;  lid = id; }
  else if (id < 2048)  { W = w_kv;  Wt = (f16*)(ws + OFF_WQKV) + 512 * 1024; K = 1024; N = 1536; lid = id - 512; }
  else if (id < 4096)  { W = w_s;   Wt = (f16*)(ws + OFF_WSC);               K = 1024; N = 2048; lid = id - 2048; }
  else if (id < 5120)  { W = w_cat; Wt = (f16*)(ws + OFF_WCAT);              K = 1024; N = 1024; lid = id - 4096; }
  else if (id < 9216)  { W = w1;    Wt = (f16*)(ws + OFF_W1);                K = 1024; N = 4096; lid = id - 5120; }
  else                 { W = w2;    Wt = (f16*)(ws + OFF_W2);                K = 4096; N = 1024; lid = id - 9216; }
  int ntx = N >> 5;
  int n0 = (lid % ntx) * 32, k0 = (lid / ntx) * 32;
  __shared__ float tile[32][33];
  int tid = threadIdx.x, r = tid >> 5, c = tid & 31;
#pragma unroll
  for (int i = 0; i < 4; ++i)
    tile[r + i * 8][c] = W[(size_t)(k0 + r + i * 8) * N + n0 + c];
  __syncthreads();
#pragma unroll
  for (int i = 0; i < 4; ++i) {
    int rr = r + i * 8;
    Wt[(size_t)(n0 + rr) * K + k0 + c] = (f16)tile[c][rr];
  }
}

__global__ void bias_concat_k(const float* __restrict__ bq, const float* __restrict__ bkv,
                              float* __restrict__ out) {
  int i = blockIdx.x * 256 + threadIdx.x;   // 2048
  out[i] = (i < 512) ? bq[i] : bkv[i - 512];
}

// ---------------- RMSNorm ----------------
__global__ __launch_bounds__(256) void rmsnorm_k(const float* __restrict__ x,
                                                 const float* __restrict__ w,
                                                 f16* __restrict__ xn) {
  int row = blockIdx.x, tid = threadIdx.x;
  float4 v = ((const float4*)(x + (size_t)row * 1024))[tid];
  float ss = v.x * v.x + v.y * v.y + v.z * v.z + v.w * v.w;
#pragma unroll
  for (int d = 1; d < 64; d <<= 1) ss += __shfl_xor(ss, d, 64);
  __shared__ float red[4];
  if ((tid & 63) == 0) red[tid >> 6] = ss;
  __syncthreads();
  float tot = red[0] + red[1] + red[2] + red[3];
  float r = rsqrtf(tot * (1.0f / 1024.0f) + 1e-6f);
  float4 wv = ((const float4*)w)[tid];
  f16x4 o;
  o[0] = (f16)(v.x * r * wv.x); o[1] = (f16)(v.y * r * wv.y);
  o[2] = (f16)(v.z * r * wv.z); o[3] = (f16)(v.w * r * wv.w);
  *(f16x4*)(xn + (size_t)row * 1024 + tid * 4) = o;
}

// XCD region mapping (bijective). NSPLIT=2 -> square-ish regions for big-B GEMMs.
template <int NSPLIT>
DEV void xcd_map(int nwgx, int nbc, int bidl, int tileM, int tileN, long& m0, long& n0) {
  int cpx = (nwgx * nbc) >> 3;
  int xcd = bidl & 7, pos = bidl >> 3;
  int rn = nbc / NSPLIT;
  int rm = cpx / rn;
  int xm = xcd / NSPLIT, xn = xcd % NSPLIT;
  int nbi = xn * rn + pos / rm;
  int mb  = xm * rm + pos % rm;
  m0 = (long)mb * tileM;
  n0 = (long)nbi * tileN;
}

// ---------------- GEMM 128x128, 4 waves, dbuf + hoisted staging addresses: MODE 2 & 7 ----
template <int MODE, int NSPLIT = 1>
__global__ __launch_bounds__(256) void gemm_k(const f16* __restrict__ A, const f16* __restrict__ Bt,
                                              const float* __restrict__ bias,
                                              float* __restrict__ outF,
                                              const float* __restrict__ resid,
                                              const float* __restrict__ rsp,
                                              int M, int N, int K, int lda, int ldb) {
  __shared__ alignas(16) char smA[2][16384];
  __shared__ alignas(16) char smB[2][16384];
  int bidl = blockIdx.y * gridDim.x + blockIdx.x;
  long m0, n0;
  xcd_map<NSPLIT>(gridDim.x, gridDim.y, bidl, 128, 128, m0, n0);
  int tid = threadIdx.x, lane = tid & 63, wv = tid >> 6, wr = wv >> 1, wc = wv & 1;
  f32x4 acc[4][4] = {};

  const char* gA[4]; const char* gB[4]; int lo[4];
  long stepA = (MODE == 7) ? 524288 : 128;
  {
    const char* Abase;
    if (MODE == 7) Abase = (const char*)(A + (((m0 >> 12) * 16) * 4096 + (m0 & 4095)) * 64);
    else           Abase = (const char*)(A + m0 * lda);
    const char* Bbase = (const char*)(Bt + n0 * ldb);
    long astr = (MODE == 7) ? 128 : (long)lda * 2;
#pragma unroll
    for (int c = 0; c < 4; ++c) {
      int P = c * 4096 + tid * 16;
      int L = P ^ (((P >> 7) & 7) << 4);
      long row = L >> 7; int colb = L & 127;
      lo[c] = c * 4096 + (tid & ~63) * 16;
      gA[c] = Abase + row * astr + colb;
      gB[c] = Bbase + row * ((long)ldb * 2) + colb;
    }
  }
  auto stageAB = [&](int buf, int t) {
#pragma unroll
    for (int c = 0; c < 4; ++c) gload_lds16(gB[c] + (long)t * 128, smB[buf] + lo[c]);
#pragma unroll
    for (int c = 0; c < 4; ++c) gload_lds16(gA[c] + (long)t * stepA, smA[buf] + lo[c]);
  };

  int T = K >> 6;
  stageAB(0, 0);
  __syncthreads();
  int cur = 0;
  for (int t = 0; t < T; ++t) {
    if (t + 1 < T) stageAB(cur ^ 1, t + 1);
#pragma unroll
    for (int kk = 0; kk < 2; ++kk) {
      int kbyte = kk * 64 + (lane >> 4) * 16;
      f16x8 aF[4], bF[4];
#pragma unroll
      for (int m = 0; m < 4; ++m) {
        int L = (wr * 64 + m * 16 + (lane & 15)) * 128 + kbyte;
        aF[m] = *(const f16x8*)(smA[cur] + (L ^ (((L >> 7) & 7) << 4)));
      }
#pragma unroll
      for (int n = 0; n < 4; ++n) {
        int L = (wc * 64 + n * 16 + (lane & 15)) * 128 + kbyte;
        bF[n] = *(const f16x8*)(smB[cur] + (L ^ (((L >> 7) & 7) << 4)));
      }
#pragma unroll
      for (int m = 0; m < 4; ++m)
#pragma unroll
        for (int n = 0; n < 4; ++n)
          acc[m][n] = __builtin_amdgcn_mfma_f32_16x16x32_f16(aF[m], bF[n], acc[m][n], 0, 0, 0);
    }
    __syncthreads();
    cur ^= 1;
  }
  float rsv = rsp[0];
#pragma unroll
  for (int m = 0; m < 4; ++m)
#pragma unroll
    for (int n = 0; n < 4; ++n) {
      long gn = n0 + wc * 64 + n * 16 + (lane & 15);
      float bv = bias[gn];
      long rbase = m0 + wr * 64 + m * 16 + (lane >> 4) * 4;
#pragma unroll
      for (int i = 0; i < 4; ++i) {
        long gm = rbase + i;
        float v = acc[m][n][i] + bv;
        long idx = gm * N + gn;
        outF[idx] = resid[idx] + v * rsv;
      }
    }
}

// ---------------- GEMM 256x256, 8 waves (2x4), dbuf + hoisted addresses: MODE 3,4; MODE 5 legacy
template <int MODE, int NSPLIT = 1>
__global__ __launch_bounds__(512) void gemm256_k(const f16* __restrict__ A, const f16* __restrict__ Bt,
                                                 const float* __restrict__ bias,
                                                 f16* __restrict__ o1, f16* __restrict__ o2,
                                                 f16* __restrict__ o3,
                                                 const float* __restrict__ resid,
                                                 int M, int N, int K, int lda, int ldb, int pp) {
  __shared__ alignas(16) char smA[2][32768];
  __shared__ alignas(16) char smB[2][32768];
  int bidl = blockIdx.y * gridDim.x + blockIdx.x;
  long m0, n0;
  xcd_map<NSPLIT>(gridDim.x, gridDim.y, bidl, 256, 256, m0, n0);
  int tid = threadIdx.x, lane = tid & 63, wv = tid >> 6;   // wv 0..7
  int wr = wv >> 2, wc = wv & 3;                            // 2 x 4 wave grid
  long t0 = 0;
  int bq = 0;
  if (MODE == 5) {
    long mbl = m0 >> 8;                        // original flat m block index
    bq = (int)(mbl >> 3); int sb = (int)(mbl & 7);
    m0 = (long)sb * 256;                       // local s base within the half
    t0 = (long)bq * 4096 + (long)pp * 2048 + m0;
  }
  f32x4 acc[8][4] = {};
  const char* Bb = (const char*)(Bt + n0 * ldb);

  if constexpr (MODE == 5) {
    auto stageAB5 = [&](int buf, int k0) {
      stage_swz512(Bb + (long)k0 * 2, (long)ldb * 2, smB[buf], 32768, 7, 7);
      int P = tid * 16;
#pragma unroll
      for (int b0 = 0; b0 < 32768; b0 += 8192) {
        int PP = b0 + P;
        int L = PP ^ (((PP >> 7) & 7) << 4);
        int row = L >> 7, colf = (L & 127) >> 1;
        const float* src = resid + (size_t)(t0 + row) * 1024 + k0 + colf;
        float4 u0 = *(const float4*)src;
        float4 u1 = *(const float4*)(src + 4);
        f16x8 o;
        o[0] = (f16)u0.x; o[1] = (f16)u0.y; o[2] = (f16)u0.z; o[3] = (f16)u0.w;
        o[4] = (f16)u1.x; o[5] = (f16)u1.y; o[6] = (f16)u1.z; o[7] = (f16)u1.w;
        *(f16x8*)(smA[buf] + PP) = o;
      }
    };
    stageAB5(0, 0);
    __syncthreads();
    int cur = 0;
    for (int k0 = 0; k0 < K; k0 += 64) {
      if (k0 + 64 < K) stageAB5(cur ^ 1, k0 + 64);
#pragma unroll
      for (int kk = 0; kk < 2; ++kk) {
        int kb2 = kk * 64 + (lane >> 4) * 16;
        f16x8 aF[8], bF[4];
#pragma unroll
        for (int m = 0; m < 8; ++m) {
          int L = (wr * 128 + m * 16 + (lane & 15)) * 128 + kb2;
          aF[m] = *(const f16x8*)(smA[cur] + (L ^ (((L >> 7) & 7) << 4)));
        }
#pragma unroll
        for (int n = 0; n < 4; ++n) {
          int L = (wc * 64 + n * 16 + (lane & 15)) * 128 + kb2;
          bF[n] = *(const f16x8*)(smB[cur] + (L ^ (((L >> 7) & 7) << 4)));
        }
#pragma unroll
        for (int m = 0; m < 8; ++m)
#pragma unroll
          for (int n = 0; n < 4; ++n)
            acc[m][n] = __builtin_amdgcn_mfma_f32_16x16x32_f16(aF[m], bF[n], acc[m][n], 0, 0, 0);
      }
      __syncthreads();
      cur ^= 1;
    }
  } else {
    const char* gA[4]; const char* gB[4]; int lo[4];
    {
      const char* Abase = (const char*)(A + m0 * lda);
#pragma unroll
      for (int c = 0; c < 4; ++c) {
        int P = c * 8192 + tid * 16;
        int L = P ^ (((P >> 7) & 7) << 4);
        long row = L >> 7; int colb = L & 127;
        lo[c] = c * 8192 + (tid & ~63) * 16;
        gA[c] = Abase + row * ((long)lda * 2) + colb;
        gB[c] = Bb + row * ((long)ldb * 2) + colb;
      }
    }
    auto stageAB = [&](int buf, int t) {
#pragma unroll
      for (int c = 0; c < 4; ++c) gload_lds16(gB[c] + (long)t * 128, smB[buf] + lo[c]);
#pragma unroll
      for (int c = 0; c < 4; ++c) gload_lds16(gA[c] + (long)t * 128, smA[buf] + lo[c]);
    };
    int T = K >> 6;
    stageAB(0, 0);
    __syncthreads();
    int cur = 0;
    for (int t = 0; t < T; ++t) {
      if (t + 1 < T) stageAB(cur ^ 1, t + 1);
#pragma unroll
      for (int kk = 0; kk < 2; ++kk) {
        int kb2 = kk * 64 + (lane >> 4) * 16;
        f16x8 aF[8], bF[4];
#pragma unroll
        for (int m = 0; m < 8; ++m) {
          int L = (wr * 128 + m * 16 + (lane & 15)) * 128 + kb2;
          aF[m] = *(const f16x8*)(smA[cur] + (L ^ (((L >> 7) & 7) << 4)));
        }
#pragma unroll
        for (int n = 0; n < 4; ++n) {
          int L = (wc * 64 + n * 16 + (lane & 15)) * 128 + kb2;
          bF[n] = *(const f16x8*)(smB[cur] + (L ^ (((L >> 7) & 7) << 4)));
        }
#pragma unroll
        for (int m = 0; m < 8; ++m)
#pragma unroll
          for (int n = 0; n < 4; ++n)
            acc[m][n] = __builtin_amdgcn_mfma_f32_16x16x32_f16(aF[m], bF[n], acc[m][n], 0, 0, 0);
      }
      __syncthreads();
      cur ^= 1;
    }
  }
#pragma unroll
  for (int m = 0; m < 8; ++m)
#pragma unroll
    for (int n = 0; n < 4; ++n) {
      long gn = n0 + wc * 64 + n * 16 + (lane & 15);
      float bv = bias[gn];
      long rbase = m0 + wr * 128 + m * 16 + (lane >> 4) * 4;
      if (MODE == 4) {
        long b = rbase >> 12, s = rbase & 4095;
        if (gn < 512) {
          long h = gn >> 5, dk = gn & 31;
#pragma unroll
          for (int i = 0; i < 4; ++i)
            o1[(((size_t)b * 16 + h) * 4096 + s + i) * 32 + dk] = (f16)(acc[m][n][i] + bv);
        } else {
          long c2 = gn - 512, h = c2 / 96, j = c2 % 96;
          if (j < 32) {
#pragma unroll
            for (int i = 0; i < 4; ++i)
              o2[(((size_t)b * 16 + h) * 4096 + s + i) * 32 + j] = (f16)(acc[m][n][i] + bv);
          } else {
            f16x4 pk;
#pragma unroll
            for (int i = 0; i < 4; ++i) pk[i] = (f16)(acc[m][n][i] + bv);
            *(f16x4*)(o3 + (((size_t)b * 16 + h) * 64 + (j - 32)) * 4096 + s) = pk;
          }
        }
      } else {
#pragma unroll
        for (int i = 0; i < 4; ++i) {
          long gm = rbase + i;
          float v = acc[m][n][i] + bv;
          if (MODE == 3) {
            float u = v * 0.7978845608028654f * (1.f + 0.044715f * v * v);
            float e = __expf(fminf(2.f * u, 80.f));
            o1[gm * N + gn] = (f16)(v * (e / (e + 1.f)));
          } else {  // MODE 5: lt[(bq*2048+gn)*2048 + s_local]
            o1[((size_t)bq * 2048 + gn) * 2048 + gm] = (f16)v;
          }
        }
      }
    }
}

// ---------------- kv_s partials: fixed-offset softmax, (nsb, s-chunk) parallel ----------------
__global__ __launch_bounds__(256) void kvs_k(const f16* __restrict__ lt,
                                             const f16* __restrict__ kh,
                                             const f16* __restrict__ vT,
                                             const float* __restrict__ mask,
                                             float* __restrict__ pacc, int pass) {
  int gx = blockIdx.x, nsb = gx & 3, sc = gx >> 2;
  int h = blockIdx.y, b = blockIdx.z;
  int bh = b * 16 + h;
  __shared__ alignas(16) char smA[4096];        // p [32 ns][64 s] swizzled
  __shared__ alignas(16) f16 smB[112][88];      // [col j][s]; rows 96..111 den/zero
  int tid = threadIdx.x, lane = tid & 63, w = tid >> 6;
  int mf = w >> 1, nb0 = (w & 1) * 4, nfr = (w & 1) ? 3 : 4;
  for (int idx = tid; idx < 16 * 64; idx += 256) {
    int r = 96 + (idx >> 6), c2 = idx & 63;
    smB[r][c2] = (r == 96) ? (f16)1.0f : (f16)0.0f;
  }
  f32x4 acc[4] = {};
  const f16* ltb = lt + ((size_t)bh * 128 + nsb * 32) * 2048;
  for (int it = 0; it < 4; ++it) {
    int sl0 = sc * 256 + it * 64;              // within-half s base
    int s0g = pass * 2048 + sl0;               // global s base
    __syncthreads();
    {   // A: p = mask>0 ? exp(l-8) : 0
      int P = tid * 16;
      int L = P ^ (((P >> 7) & 7) << 4);
      int row = L >> 7, colf = (L & 127) >> 1;
      f16x8 lv = *(const f16x8*)(ltb + (size_t)row * 2048 + sl0 + colf);
      const float* mrow = mask + (size_t)b * 4096 + s0g + colf;
      float4 m0v = *(const float4*)mrow, m1v = *(const float4*)(mrow + 4);
      float mm[8] = {m0v.x, m0v.y, m0v.z, m0v.w, m1v.x, m1v.y, m1v.z, m1v.w};
      f16x8 o;
#pragma unroll
      for (int j = 0; j < 8; ++j)
        o[j] = (f16)((mm[j] > 0.f) ? expf((float)lv[j] - 8.0f) : 0.0f);
      *(f16x8*)(smA + P) = o;
    }
    {   // B: k part -> rows 0..31
      int sl = tid >> 2, jg = (tid & 3) * 8;
      f16x8 u = *(const f16x8*)(kh + ((size_t)bh * 4096 + s0g + sl) * 32 + jg);
#pragma unroll
      for (int j = 0; j < 8; ++j) smB[jg + j][sl] = u[j];
    }
#pragma unroll
    for (int half = 0; half < 2; ++half) {   // B: v part (vT, vectorized) -> rows 32..95
      int task = tid + half * 256;
      int dv = task >> 3, sl0v = (task & 7) * 8;
      f16x8 u = *(const f16x8*)(vT + ((size_t)bh * 64 + dv) * 4096 + s0g + sl0v);
      *(f16x8*)(&smB[32 + dv][sl0v]) = u;
    }
    __syncthreads();
#pragma unroll
    for (int kk = 0; kk < 2; ++kk) {
      int kbyte = kk * 64 + (lane >> 4) * 16;
      int L = (mf * 16 + (lane & 15)) * 128 + kbyte;
      f16x8 aF = *(const f16x8*)(smA + (L ^ (((L >> 7) & 7) << 4)));
#pragma unroll
      for (int n = 0; n < 4; ++n)
        if (n < nfr) {
          f16x8 bF = *(const f16x8*)((const char*)smB + ((nb0 + n) * 16 + (lane & 15)) * 176 + kbyte);
          acc[n] = __builtin_amdgcn_mfma_f32_16x16x32_f16(aF, bF, acc[n], 0, 0, 0);
        }
    }
  }
  int slot = pass * 8 + sc;
  float* pb = pacc + (((size_t)bh * 4 + nsb) * 16 + slot) * 3584;
#pragma unroll
  for (int n = 0; n < 4; ++n)
    if (n < nfr) {
      int col = (nb0 + n) * 16 + (lane & 15);
#pragma unroll
      for (int i = 0; i < 4; ++i) {
        int nsrow = mf * 16 + (lane >> 4) * 4 + i;
        pb[(size_t)nsrow * 112 + col] = acc[n][i];
      }
    }
}

__global__ __launch_bounds__(256) void kvs_fin_k(const float* __restrict__ pacc,
                                                 f16* __restrict__ ks, f16* __restrict__ vst) {
  int bh = blockIdx.x, tid = threadIdx.x;
  __shared__ float den[128];
  const float* base = pacc + (size_t)bh * 4 * 16 * 3584;
  if (tid < 128) {
    int nsb = tid >> 5, nsl = tid & 31;
    float d = 0.f;
#pragma unroll
    for (int slot = 0; slot < 16; ++slot)
      d += base[((size_t)nsb * 16 + slot) * 3584 + (size_t)nsl * 112 + 96];
    den[tid] = d;
  }
  __syncthreads();
  for (int e = tid; e < 12288; e += 256) {
    int ns = e / 96, j = e % 96;
    int nsb = ns >> 5, nsl = ns & 31;
    float sv = 0.f;
#pragma unroll
    for (int slot = 0; slot < 16; ++slot)
      sv += base[((size_t)nsb * 16 + slot) * 3584 + (size_t)nsl * 112 + j];
    float v = sv / den[ns];
    if (j < 32) ks[((size_t)bh * 128 + ns) * 32 + j] = (f16)v;
    else        vst[((size_t)bh * 64 + (j - 32)) * 128 + ns] = (f16)v;
  }
}

// ---------------- merged attention, QBLK=64, single-buffer, no-max softmax ----------------
__global__ __launch_bounds__(256) void att_k(const f16* __restrict__ qh,
                                             const f16* __restrict__ kh,
                                             const f16* __restrict__ vTh,
                                             const f16* __restrict__ ksb,
                                             const f16* __restrict__ vstb,
                                             f16* __restrict__ xatt) {
  int ntj = blockIdx.x, h = blockIdx.y, b = blockIdx.z;
  int nt = ((ntj & 7) << 3) | (ntj >> 3);     // 64 q-tiles, 8 consecutive per XCD
  int bh = b * 16 + h, s0 = nt * 64;
  __shared__ alignas(16) char smQ[4096];      // Q [64 q][32 dk] swz6/3
  __shared__ alignas(16) char smK[4096];      // K chunk [64 k][32 dk] swz6/3
  __shared__ alignas(16) char smV[8192];      // V^T chunk [64 dv][64 k] swz7/7
  __shared__ alignas(16) f16 smP[4][16][72];  // per-wave P [16 q][64 k]
  int tid = threadIdx.x, lane = tid & 63, w = tid >> 6;
  const float scale = 0.17677669529663687f;
  stage_swz((const char*)(qh + ((size_t)bh * 4096 + s0) * 32), 64, smQ, 4096, 6, 3);

  float lrun[4], l1[4];
#pragma unroll
  for (int i = 0; i < 4; ++i) { lrun[i] = 0.f; l1[i] = 0.f; }
  f32x4 o2[4] = {}, o1[4] = {};

  // 5 uniform chunks: 0..2 window (key base s0-128/s0-64/s0), 3..4 summary
  for (int c = 0; c < 5; ++c) {
    bool win = (c < 3);
    long kb = (long)s0 + (c - 2) * 64;
    if (win && kb < 0) continue;              // block-uniform
    __syncthreads();                          // prior PV reads of smK/smV done
    if (win) {
      stage_swz((const char*)(kh + ((size_t)bh * 4096 + kb) * 32), 64, smK, 4096, 6, 3);
      stage_swz((const char*)(vTh + (size_t)bh * 64 * 4096 + kb), 8192, smV, 8192, 7, 7);
    } else {
      int sc = c - 3;
      stage_swz((const char*)(ksb + ((size_t)bh * 128 + sc * 64) * 32), 64, smK, 4096, 6, 3);
      stage_swz((const char*)(vstb + (size_t)bh * 64 * 128 + sc * 64), 256, smV, 8192, 7, 7);
    }
    __syncthreads();                          // K+V (and Q on first iter) staged
    // QK^T: 16 q-rows per wave x 64 keys
    f32x4 s[4] = {};
    {
      int kbyte = (lane >> 4) * 16;
      int Lq = (w * 16 + (lane & 15)) * 64 + kbyte;
      f16x8 aF = *(const f16x8*)(smQ + (Lq ^ (((Lq >> 6) & 3) << 4)));
#pragma unroll
      for (int n = 0; n < 4; ++n) {
        int Lk = (n * 16 + (lane & 15)) * 64 + kbyte;
        f16x8 bF = *(const f16x8*)(smK + (Lk ^ (((Lk >> 6) & 3) << 4)));
        s[n] = __builtin_amdgcn_mfma_f32_16x16x32_f16(aF, bF, s[n], 0, 0, 0);
      }
    }
    // no-max softmax accumulate (window and summary keep separate l/o)
    float* lr = win ? lrun : l1;
    f32x4* oo = win ? o2 : o1;
#pragma unroll
    for (int i = 0; i < 4; ++i) {
      int a2 = w * 16 + (lane >> 4) * 4 + i;
      float sum = 0.f;
#pragma unroll
      for (int n = 0; n < 4; ++n) {
        int kl = n * 16 + (lane & 15);
        bool valid = !win || (c == 1) || (c == 0 ? (kl >= a2) : (kl <= a2));
        float p = valid ? __expf(fminf(s[n][i] * scale, 10.f)) : 0.f;
        s[n][i] = p; sum += p;
      }
      lr[i] += wave16_sum(sum);
    }
    // P -> per-wave LDS slice (same-wave dependency; no block barrier needed)
#pragma unroll
    for (int n = 0; n < 4; ++n)
#pragma unroll
      for (int i = 0; i < 4; ++i)
        smP[w][(lane >> 4) * 4 + i][n * 16 + (lane & 15)] = (f16)s[n][i];
    // PV: K-dim 64 -> 2 mfma steps
#pragma unroll
    for (int kk = 0; kk < 2; ++kk) {
      int kb2 = kk * 64 + (lane >> 4) * 16;
      f16x8 aP = *(const f16x8*)((const char*)smP[w] + (lane & 15) * 144 + kb2);
#pragma unroll
      for (int n = 0; n < 4; ++n) {
        int dv = n * 16 + (lane & 15);
        int Lv = dv * 128 + kb2;
        f16x8 bV = *(const f16x8*)(smV + (Lv ^ (((Lv >> 7) & 7) << 4)));
        oo[n] = __builtin_amdgcn_mfma_f32_16x16x32_f16(aP, bV, oo[n], 0, 0, 0);
      }
    }
  }
  // epilogue: contiguous head-blocked write
  f16* xb = xatt + ((size_t)bh * 4096 + s0) * 64;
#pragma unroll
  for (int n = 0; n < 4; ++n)
#pragma unroll
    for (int i = 0; i < 4; ++i) {
      int row = w * 16 + (lane >> 4) * 4 + i, dv = n * 16 + (lane & 15);
      xb[(size_t)row * 64 + dv] = (f16)(o2[n][i] / lrun[i] + o1[n][i] / l1[i]);
    }
}

// ---------------- diagnostic sentinel ----------------
__global__ void sentinel_k(float* out, size_t n, float val) {
  size_t i = (size_t)blockIdx.x * 256 + threadIdx.x;
  size_t stride = (size_t)gridDim.x * 256;
  for (; i < n; i += stride) out[i] = val;
}

extern "C" void kernel_launch(void* const* d_in, const int* in_sizes, int n_in,
                              void* d_out, int out_size, void* d_ws, size_t ws_size,
                              hipStream_t stream) {
  float* xo = (float*)d_out;
  if (ws_size < WS_NEED) {   // diagnostic: encode ws_size into the output
    float val = -(1000.0f + (float)(ws_size / 1000000ull));
    sentinel_k<<<2048, 256, 0, stream>>>(xo, (size_t)out_size, val);
    return;
  }
  const float* x     = (const float*)d_in[0];
  const float* mask  = (const float*)d_in[1];
  const float* rsp   = (const float*)d_in[2];
  const float* w_q   = (const float*)d_in[3];
  const float* b_q   = (const float*)d_in[4];
  const float* w_kv  = (const float*)d_in[5];
  const float* b_kv  = (const float*)d_in[6];
  const float* w_s   = (const float*)d_in[7];
  const float* b_s   = (const float*)d_in[8];
  const float* w_cat = (const float*)d_in[9];
  const float* b_cat = (const float*)d_in[10];
  const float* n1w   = (const float*)d_in[11];
  const float* n2w   = (const float*)d_in[12];
  const float* w1    = (const float*)d_in[13];
  const float* b1    = (const float*)d_in[14];
  const float* w2    = (const float*)d_in[15];
  const float* b2    = (const float*)d_in[16];
  char* ws = (char*)d_ws;

  f16*   wqkv_t = (f16*)(ws + OFF_WQKV);
  f16*   ws_t   = (f16*)(ws + OFF_WSC);
  f16*   wcat_t = (f16*)(ws + OFF_WCAT);
  f16*   w1_t   = (f16*)(ws + OFF_W1);
  f16*   w2_t   = (f16*)(ws + OFF_W2);
  float* bqkv   = (float*)(ws + OFF_BQKV);
  f16*   q_h    = (f16*)(ws + OFF_Q);
  f16*   k_h    = (f16*)(ws + OFF_K);
  f16*   h_h    = (f16*)(ws + OFF_Q);     // alias: q+k dead at MLP time
  f16*   xn_h   = (f16*)(ws + OFF_P1);
  f16*   lt16   = (f16*)(ws + OFF_P1);    // alias: xn dead after qkv gemm
  f16*   xatt_h = (f16*)(ws + OFF_P1);    // alias: lt dead after kvs
  f16*   g_h    = (f16*)(ws + OFF_P1);    // alias: spans P1+VT at MLP time (67 MB)
  f16*   vT_h   = (f16*)(ws + OFF_VT);
  f16*   ks_h   = (f16*)(ws + OFF_KS);
  f16*   vst_h  = (f16*)(ws + OFF_VST);

  // weight prep: one launch for all transposes + bias concat
  wcast_all_k<<<13312, 256, 0, stream>>>(w_q, w_kv, w_s, w_cat, w1, w2, ws);
  bias_concat_k<<<8, 256, 0, stream>>>(b_q, b_kv, bqkv);

  // norm1 -> xn
  rmsnorm_k<<<Tq, 256, 0, stream>>>(x, n1w, xn_h);
  // qkv projection (256² dbuf) -> q/k f16, v transposed f16
  gemm256_k<4><<<dim3(64, 8), 512, 0, stream>>>(xn_h, wqkv_t, bqkv, q_h, k_h, vT_h,
                                                nullptr, Tq, 2048, 1024, 1024, 1024, 0);
  // summary path: two s-halves; kvs partials go to d_out scratch (dead until out-proj)
  for (int p = 0; p < 2; ++p) {
    gemm256_k<5><<<dim3(32, 8), 512, 0, stream>>>(nullptr, ws_t, b_s, lt16, nullptr, nullptr,
                                                  x, 8192, 2048, 1024, 0, 1024, p);
    kvs_k<<<dim3(32, 16, 4), 256, 0, stream>>>(lt16, k_h, vT_h, mask, xo, p);
  }
  kvs_fin_k<<<64, 256, 0, stream>>>(xo, ks_h, vst_h);
  // merged attention (QBLK=64, no-max softmax) -> xatt [b][h][s][64] (over lt)
  att_k<<<dim3(64, 16, 4), 256, 0, stream>>>(q_h, k_h, vT_h, ks_h, vst_h, xatt_h);
  // out projection + residual -> d_out (f32); A head-blocked (128² dbuf, 1024 blocks)
  gemm_k<7><<<dim3(128, 8), 256, 0, stream>>>(xatt_h, wcat_t, b_cat, xo,
                                              x, rsp, Tq, 1024, 1024, 0, 1024);
  // MLP: norm2 -> h (over q+k); two M-chunks of 8192 tokens, g = 67 MB arena
  // NSPLIT=2: square-ish XCD regions so the 8 MB B matrices become L2-resident.
  rmsnorm_k<<<Tq, 256, 0, stream>>>(xo, n2w, h_h);
  for (int mc = 0; mc < 2; ++mc) {
    const f16* hA = h_h + (size_t)mc * 8192 * 1024;
    float* xoc = xo + (size_t)mc * 8192 * 1024;
    gemm256_k<3, 2><<<dim3(32, 16), 512, 0, stream>>>(hA, w1_t, b1, g_h, nullptr, nullptr,
                                                      nullptr, 8192, 4096, 1024, 1024, 1024, 0);
    gemm_k<2, 2><<<dim3(64, 8), 256, 0, stream>>>(g_h, w2_t, b2, xoc,
                                                  xoc, rsp, 8192, 1024, 4096, 4096, 4096);
  }
}